// Round 7
// baseline (1030.470 us; speedup 1.0000x reference)
//
#include <hip/hip_runtime.h>
#include <math.h>

#define HH 128      // hidden
#define DD 2048     // input size
#define BATCH 64
#define TT 256
#define G4 512      // 4*H
#define GB 16       // batches per recurrence block (4 blocks)
#define HPAD 136    // padded h row length (halves)

typedef __attribute__((ext_vector_type(8))) short bf16x8;   // 8 bf16
typedef __attribute__((ext_vector_type(4))) float f32x4;
typedef _Float16 f16x8 __attribute__((ext_vector_type(8))); // 8 fp16

// xp layout (permuted for coalesced recurrence loads):
//   elem(t, b, n')  with blk=b>>4, lb=b&15, w=n'>>6, mm=(n'>>4)&3, low=n'&15
//   addr = t*32768 + blk*8192 + w*1024 + mm*256 + lb*16 + low
// n' = 4u+g (gate-interleaved): original gate row = g*128+u.

// ---- helpers ---------------------------------------------------------------
static __device__ __forceinline__ unsigned short f2bf_rne(float f) {
    union { float f; unsigned u; } v; v.f = f;
    unsigned r = v.u + 0x7fff + ((v.u >> 16) & 1);
    return (unsigned short)(r >> 16);
}
static __device__ __forceinline__ float bf2f(unsigned short b) {
    union { unsigned u; float f; } v; v.u = ((unsigned)b) << 16;
    return v.f;
}
static __device__ __forceinline__ float fexp2(float x) {
#if __has_builtin(__builtin_amdgcn_exp2f)
    return __builtin_amdgcn_exp2f(x);
#else
    return exp2f(x);
#endif
}
static __device__ __forceinline__ float frcp(float x) {
#if __has_builtin(__builtin_amdgcn_rcpf)
    return __builtin_amdgcn_rcpf(x);
#else
    return 1.f / x;
#endif
}
static __device__ __forceinline__ float sigmoid_f(float x) {
    return frcp(1.f + fexp2(-1.44269504f * x));
}
static __device__ __forceinline__ float tanh_f(float x) {
    float xx = fminf(fmaxf(x, -15.f), 15.f);
    float e = fexp2(2.88539008f * xx);               // exp(2x)
    return 1.f - 2.f * frcp(e + 1.f);
}

// ---------------------------------------------------------------------------
// Split-bf16 GEMM (validated R2-R6): xp(t,b,n') permuted output.
// ---------------------------------------------------------------------------
#define PK 40   // LDS row stride in halves (80 B)

__global__ __launch_bounds__(256) void gemm_split_bf16(
    const float* __restrict__ A, const float* __restrict__ Bw,
    const float* __restrict__ b1, const float* __restrict__ b2,
    float* __restrict__ C, int M, int N, int K)
{
    __shared__ unsigned short Ah[128 * PK], Al[128 * PK];
    __shared__ unsigned short Bh[128 * PK], Bl[128 * PK];

    const int tid = threadIdx.x;
    const int l = tid & 63;
    const int w = tid >> 6;
    const int wr = w >> 1, wc = w & 1;
    const int bm = blockIdx.y, bn = blockIdx.x;

    f32x4 acc[4][4];
#pragma unroll
    for (int m = 0; m < 4; ++m)
#pragma unroll
        for (int n = 0; n < 4; ++n) acc[m][n] = f32x4{0.f, 0.f, 0.f, 0.f};

    const float* Ab = A + (size_t)(bm * 128) * K;

    for (int k0 = 0; k0 < K; k0 += 32) {
        __syncthreads();
#pragma unroll
        for (int q = 0; q < 4; ++q) {
            int fid = tid + 256 * q;
            int r = fid >> 3;
            int kk = (fid & 7) << 2;
            int n = bn * 128 + r;
            int orign = ((n & 3) << 7) | (n >> 2);
            float4 av = *(const float4*)(Ab + (size_t)r * K + k0 + kk);
            float4 bv = *(const float4*)(Bw + (size_t)orign * K + k0 + kk);
            float a4[4] = {av.x, av.y, av.z, av.w};
            float b4[4] = {bv.x, bv.y, bv.z, bv.w};
            ushort4 ahv, alv, bhv, blv;
            unsigned short t;
            t = f2bf_rne(a4[0]); ahv.x = t; alv.x = f2bf_rne(a4[0] - bf2f(t));
            t = f2bf_rne(a4[1]); ahv.y = t; alv.y = f2bf_rne(a4[1] - bf2f(t));
            t = f2bf_rne(a4[2]); ahv.z = t; alv.z = f2bf_rne(a4[2] - bf2f(t));
            t = f2bf_rne(a4[3]); ahv.w = t; alv.w = f2bf_rne(a4[3] - bf2f(t));
            t = f2bf_rne(b4[0]); bhv.x = t; blv.x = f2bf_rne(b4[0] - bf2f(t));
            t = f2bf_rne(b4[1]); bhv.y = t; blv.y = f2bf_rne(b4[1] - bf2f(t));
            t = f2bf_rne(b4[2]); bhv.z = t; blv.z = f2bf_rne(b4[2] - bf2f(t));
            t = f2bf_rne(b4[3]); bhv.w = t; blv.w = f2bf_rne(b4[3] - bf2f(t));
            int off = r * PK + kk;
            *(ushort4*)&Ah[off] = ahv;
            *(ushort4*)&Al[off] = alv;
            *(ushort4*)&Bh[off] = bhv;
            *(ushort4*)&Bl[off] = blv;
        }
        __syncthreads();

        bf16x8 aH[4], aL[4], bH[4], bL[4];
#pragma unroll
        for (int m = 0; m < 4; ++m) {
            int row = wr * 64 + m * 16 + (l & 15);
            int off = row * PK + 8 * (l >> 4);
            aH[m] = *(const bf16x8*)&Ah[off];
            aL[m] = *(const bf16x8*)&Al[off];
        }
#pragma unroll
        for (int n = 0; n < 4; ++n) {
            int row = wc * 64 + n * 16 + (l & 15);
            int off = row * PK + 8 * (l >> 4);
            bH[n] = *(const bf16x8*)&Bh[off];
            bL[n] = *(const bf16x8*)&Bl[off];
        }
#pragma unroll
        for (int m = 0; m < 4; ++m)
#pragma unroll
            for (int n = 0; n < 4; ++n) {
                acc[m][n] = __builtin_amdgcn_mfma_f32_16x16x32_bf16(aH[m], bH[n], acc[m][n], 0, 0, 0);
                acc[m][n] = __builtin_amdgcn_mfma_f32_16x16x32_bf16(aH[m], bL[n], acc[m][n], 0, 0, 0);
                acc[m][n] = __builtin_amdgcn_mfma_f32_16x16x32_bf16(aL[m], bH[n], acc[m][n], 0, 0, 0);
            }
    }

#pragma unroll
    for (int n = 0; n < 4; ++n) {
        int cg = bn * 128 + wc * 64 + n * 16 + (l & 15);
        int orig = ((cg & 3) << 7) | (cg >> 2);
        float bias = b1[orig] + b2[orig];
        size_t cbase = (size_t)(cg >> 6) * 1024 + ((cg >> 4) & 3) * 256 + (cg & 15);
#pragma unroll
        for (int m = 0; m < 4; ++m) {
            int r0 = bm * 128 + wr * 64 + m * 16 + ((l >> 4) << 2);
            f32x4 v = acc[m][n];
#pragma unroll
            for (int i = 0; i < 4; ++i) {
                int r = r0 + i;
                int t = r & 255, b = r >> 8;
                C[(size_t)t * 32768 + (size_t)(b >> 4) * 8192 + cbase + (b & 15) * 16] = v[i] + bias;
            }
        }
    }
}

// ---------------------------------------------------------------------------
// bias1p[n'] = bih1[orig]+bhh1[orig], permuted to gate-interleaved order.
// ---------------------------------------------------------------------------
__global__ void prep_bias1(const float* __restrict__ bih1,
                           const float* __restrict__ bhh1,
                           float* __restrict__ bias1p)
{
    int n = threadIdx.x;                 // 512
    int orig = ((n & 3) << 7) | (n >> 2);
    bias1p[n] = bih1[orig] + bhh1[orig];
}

// ---------------------------------------------------------------------------
// FUSED two-layer LSTM recurrence, wavefront-pipelined.
// Phase p: gates0 = xp0[p+1] + Whh0@h0_p ; gates1 = bias1 + Wih1@h0_p + Whh1@h1_{p-1}
// R7: __launch_bounds__(512,1) -> 256-VGPR budget (R6's 128-cap spilled the
// 192-VGPR weight set to scratch: VGPR_Count=128, 590us). Layer passes are
// SEQUENCED (a0 finished+retired before a1 starts) so only one f32x4[4] acc
// set is live at a time; h0 B-frags are re-read from LDS for the Wih1 pass
// (+4 ds_read_b128/thread/phase, LDS pipe has headroom). Peak live ~248 VGPR.
// ---------------------------------------------------------------------------
__global__ __launch_bounds__(512, 1) void lstm_fused(
    const float* __restrict__ xp,      // permuted xp0 layout (see top)
    const float* __restrict__ Whh0,    // [512,128] original layout
    const float* __restrict__ Wih1,    // [512,128]
    const float* __restrict__ Whh1,    // [512,128]
    const float* __restrict__ bias1p,  // [512] permuted (prep_bias1)
    const float* __restrict__ Wfc,     // [128]
    const float* __restrict__ bfc,     // [1]
    float* __restrict__ out)           // [64]
{
    const int tid = threadIdx.x;
    const int l  = tid & 63;
    const int w  = tid >> 6;     // wave 0..7
    const int lb = l & 15;       // batch lane / MFMA col
    const int lg = l >> 4;       // 0..3
    const int blk = blockIdx.x;

    __shared__ ushort h0b[2][GB][HPAD];
    __shared__ ushort h1b[2][GB][HPAD];
    __shared__ float red[8][GB];

    for (int i = tid; i < 2 * GB * HPAD; i += 512) {
        ((ushort*)h0b)[i] = 0;
        ((ushort*)h1b)[i] = 0;
    }

    // ---- resident weight fragments (fp16), gate-interleaved permutation ---
    // row rp = (w*4+mm)*16 + lb  ->  orig = g*128+u ; K-slice = kt*32 + lg*8
    f16x8 wf0[4][4], wi1[4][4], wh1[4][4];     // [mm][kt], 64 VGPR each = 192
#pragma unroll
    for (int mm = 0; mm < 4; ++mm) {
        int rp = (w * 4 + mm) * 16 + lb;
        int orig = ((rp & 3) << 7) | (rp >> 2);
#pragma unroll
        for (int kt = 0; kt < 4; ++kt) {
            const float* p0 = Whh0 + (size_t)orig * HH + kt * 32 + lg * 8;
            const float* p1 = Wih1 + (size_t)orig * HH + kt * 32 + lg * 8;
            const float* p2 = Whh1 + (size_t)orig * HH + kt * 32 + lg * 8;
            float4 a0 = *(const float4*)p0, a1 = *(const float4*)(p0 + 4);
            float4 b0 = *(const float4*)p1, b1v = *(const float4*)(p1 + 4);
            float4 c0v = *(const float4*)p2, c1v = *(const float4*)(p2 + 4);
            f16x8 f;
            f[0]=(_Float16)a0.x; f[1]=(_Float16)a0.y; f[2]=(_Float16)a0.z; f[3]=(_Float16)a0.w;
            f[4]=(_Float16)a1.x; f[5]=(_Float16)a1.y; f[6]=(_Float16)a1.z; f[7]=(_Float16)a1.w;
            wf0[mm][kt] = f;
            f[0]=(_Float16)b0.x; f[1]=(_Float16)b0.y; f[2]=(_Float16)b0.z; f[3]=(_Float16)b0.w;
            f[4]=(_Float16)b1v.x; f[5]=(_Float16)b1v.y; f[6]=(_Float16)b1v.z; f[7]=(_Float16)b1v.w;
            wi1[mm][kt] = f;
            f[0]=(_Float16)c0v.x; f[1]=(_Float16)c0v.y; f[2]=(_Float16)c0v.z; f[3]=(_Float16)c0v.w;
            f[4]=(_Float16)c1v.x; f[5]=(_Float16)c1v.y; f[6]=(_Float16)c1v.z; f[7]=(_Float16)c1v.w;
            wh1[mm][kt] = f;
        }
    }

    const float* xbase = xp + (size_t)blk * 8192 + w * 1024 + lb * 16 + lg * 4;
    const int ubase = w * 16 + lg;     // u(mm) = ubase + mm*4

    f32x4 X[4];
#pragma unroll
    for (int mm = 0; mm < 4; ++mm) X[mm] = *(const f32x4*)(xbase + mm * 256);

    float c0[4] = {0.f,0.f,0.f,0.f}, c1[4] = {0.f,0.f,0.f,0.f}, hv[4];
    __syncthreads();   // LDS zeroing complete

    // ---- prologue: h0_0 = act(xp0[0]) (h_{-1}=0, c_{-1}=0) ----------------
#pragma unroll
    for (int mm = 0; mm < 4; ++mm) {
        float iv = sigmoid_f(X[mm][0]);
        float fv = sigmoid_f(X[mm][1]);
        float gg = tanh_f(X[mm][2]);
        float ov = sigmoid_f(X[mm][3]);
        float c = iv * gg;
        c0[mm] = c;
        float h = ov * tanh_f(c);
        union { _Float16 f; ushort s; } hc; hc.f = (_Float16)h;
        h0b[0][lb][ubase + mm * 4] = hc.s;
    }
#pragma unroll
    for (int mm = 0; mm < 4; ++mm)
        X[mm] = *(const f32x4*)(xbase + 32768 + mm * 256);     // xp0[1]
    __syncthreads();   // h0_0 visible

    // ---- main loop: 256 phases --------------------------------------------
    for (int p = 0; p < TT; ++p) {
        const int rb = p & 1, wb = rb ^ 1;

        // ===== layer 0: gates0 = xp0[p+1] + Whh0 @ h0_p ====================
        f32x4 a0[4];
#pragma unroll
        for (int mm = 0; mm < 4; ++mm) a0[mm] = X[mm];
        // issue next X load immediately (consumed top of phase p+1)
        {
            int tn = (p + 2 < TT) ? p + 2 : TT - 1;
#pragma unroll
            for (int mm = 0; mm < 4; ++mm)
                X[mm] = *(const f32x4*)(xbase + (size_t)tn * 32768 + mm * 256);
        }
#pragma unroll
        for (int kt = 0; kt < 4; ++kt) {
            union { uint4 u; f16x8 h; } cvt;
            cvt.u = *(const uint4*)&h0b[rb][lb][kt * 32 + lg * 8];
            f16x8 bh = cvt.h;
#pragma unroll
            for (int mm = 0; mm < 4; ++mm)
                a0[mm] = __builtin_amdgcn_mfma_f32_16x16x32_f16(wf0[mm][kt], bh, a0[mm], 0, 0, 0);
        }
#pragma unroll
        for (int mm = 0; mm < 4; ++mm) {
            float iv = sigmoid_f(a0[mm][0]);
            float fv = sigmoid_f(a0[mm][1]);
            float gg = tanh_f(a0[mm][2]);
            float ov = sigmoid_f(a0[mm][3]);
            float c = fmaf(fv, c0[mm], iv * gg);
            c0[mm] = c;
            float h = ov * tanh_f(c);
            union { _Float16 f; ushort s; } hc; hc.f = (_Float16)h;
            h0b[wb][lb][ubase + mm * 4] = hc.s;
        }
        // retire a0 before a1 starts (cap peak VGPR ~248, not ~280)
        __builtin_amdgcn_sched_barrier(0);

        // ===== layer 1: gates1 = bias1 + Wih1 @ h0_p + Whh1 @ h1_{p-1} =====
        f32x4 a1[4];
#pragma unroll
        for (int mm = 0; mm < 4; ++mm)
            a1[mm] = *(const f32x4*)(bias1p + (w * 4 + mm) * 16 + lg * 4);
#pragma unroll
        for (int kt = 0; kt < 4; ++kt) {
            union { uint4 u; f16x8 h; } cvt;
            cvt.u = *(const uint4*)&h0b[rb][lb][kt * 32 + lg * 8];
            f16x8 bh = cvt.h;
#pragma unroll
            for (int mm = 0; mm < 4; ++mm)
                a1[mm] = __builtin_amdgcn_mfma_f32_16x16x32_f16(wi1[mm][kt], bh, a1[mm], 0, 0, 0);
        }
#pragma unroll
        for (int kt = 0; kt < 4; ++kt) {
            union { uint4 u; f16x8 h; } cvt;
            cvt.u = *(const uint4*)&h1b[rb][lb][kt * 32 + lg * 8];
            f16x8 bh = cvt.h;
#pragma unroll
            for (int mm = 0; mm < 4; ++mm)
                a1[mm] = __builtin_amdgcn_mfma_f32_16x16x32_f16(wh1[mm][kt], bh, a1[mm], 0, 0, 0);
        }
#pragma unroll
        for (int mm = 0; mm < 4; ++mm) {
            float iv = sigmoid_f(a1[mm][0]);
            float fv = sigmoid_f(a1[mm][1]);
            float gg = tanh_f(a1[mm][2]);
            float ov = sigmoid_f(a1[mm][3]);
            float c = fmaf(fv, c1[mm], iv * gg);
            c1[mm] = c;
            float h = ov * tanh_f(c);
            hv[mm] = h;
            union { _Float16 f; ushort s; } hc; hc.f = (_Float16)h;
            h1b[wb][lb][ubase + mm * 4] = hc.s;
        }
        __syncthreads();
    }

    // ---- fused FC head: out[b] = sum_u h1_255[u]*Wfc[u] + bfc -------------
    float pr = 0.f;
#pragma unroll
    for (int mm = 0; mm < 4; ++mm)
        pr = fmaf(hv[mm], Wfc[ubase + mm * 4], pr);
    pr += __shfl_xor(pr, 16, 64);
    pr += __shfl_xor(pr, 32, 64);
    if (l < GB) red[w][l] = pr;
    __syncthreads();
    if (tid < GB) {
        float s = bfc[0];
#pragma unroll
        for (int q = 0; q < 8; ++q) s += red[q][tid];
        out[blk * GB + tid] = s;
    }
}

// ---------------------------------------------------------------------------
extern "C" void kernel_launch(void* const* d_in, const int* in_sizes, int n_in,
                              void* d_out, int out_size, void* d_ws, size_t ws_size,
                              hipStream_t stream)
{
    const float* x    = (const float*)d_in[0];
    const float* Wih0 = (const float*)d_in[1];
    const float* Whh0 = (const float*)d_in[2];
    const float* bih0 = (const float*)d_in[3];
    const float* bhh0 = (const float*)d_in[4];
    const float* Wih1 = (const float*)d_in[5];
    const float* Whh1 = (const float*)d_in[6];
    const float* bih1 = (const float*)d_in[7];
    const float* bhh1 = (const float*)d_in[8];
    const float* Wfc  = (const float*)d_in[9];
    const float* bfc  = (const float*)d_in[10];
    float* out = (float*)d_out;

    const int M = BATCH * TT;                    // 16384
    float* xp      = (float*)d_ws;               // [16384,512] permuted
    float* bias1p  = xp + (size_t)M * G4;        // [512]

    // 1) xp0 = x @ Wih0_perm^T + bih0 + bhh0 -> permuted layout (34.4 GFLOP)
    gemm_split_bf16<<<dim3(G4 / 128, M / 128), 256, 0, stream>>>(
        x, Wih0, bih0, bhh0, xp, M, G4, DD);

    // 2) permuted layer-1 bias
    prep_bias1<<<1, G4, 0, stream>>>(bih1, bhh1, bias1p);

    // 3) fused 2-layer recurrence + FC head
    lstm_fused<<<BATCH / GB, 512, 0, stream>>>(
        xp, Whh0, Wih1, Whh1, bias1p, Wfc, bfc, out);
}

// Round 8
// 872.098 us; speedup vs baseline: 1.1816x; 1.1816x over previous
//
#include <hip/hip_runtime.h>
#include <math.h>

#define HH 128      // hidden
#define DD 2048     // input size
#define BATCH 64
#define TT 256
#define G4 512      // 4*H
#define GB 16       // batches per recurrence block (4 blocks)
#define HPAD 136    // padded h row length (halves); rows 272B = 16B-aligned

typedef __attribute__((ext_vector_type(8))) short bf16x8;   // 8 bf16
typedef __attribute__((ext_vector_type(4))) float f32x4;
typedef _Float16 f16x8 __attribute__((ext_vector_type(8))); // 8 fp16

// xp layout (permuted for coalesced recurrence loads):
//   elem(t, b, n')  with blk=b>>4, lb=b&15
//   addr = t*32768 + blk*8192 + (n'>>6)*1024 + ((n'>>4)&3)*256 + lb*16 + (n'&15)
// n' = 4u+g (gate-interleaved): original gate row = g*128+u.

// ---- helpers ---------------------------------------------------------------
static __device__ __forceinline__ unsigned cvt_pk_bf16(float a, float b) {
    unsigned r;
    asm("v_cvt_pk_bf16_f32 %0, %1, %2" : "=v"(r) : "v"(a), "v"(b));
    return r;   // lo16 = bf16(a), hi16 = bf16(b), RNE
}
static __device__ __forceinline__ float fexp2(float x) {
#if __has_builtin(__builtin_amdgcn_exp2f)
    return __builtin_amdgcn_exp2f(x);
#else
    return exp2f(x);
#endif
}
static __device__ __forceinline__ float frcp(float x) {
#if __has_builtin(__builtin_amdgcn_rcpf)
    return __builtin_amdgcn_rcpf(x);
#else
    return 1.f / x;
#endif
}
static __device__ __forceinline__ float sigmoid_f(float x) {
    return frcp(1.f + fexp2(-1.44269504f * x));
}
static __device__ __forceinline__ float tanh_f(float x) {
    float xx = fminf(fmaxf(x, -15.f), 15.f);
    float e = fexp2(2.88539008f * xx);               // exp(2x)
    return 1.f - 2.f * frcp(e + 1.f);
}
static __device__ __forceinline__ ushort hbits(float h) {
    union { _Float16 f; ushort s; } u; u.f = (_Float16)h; return u.s;
}
// full LSTM cell pointwise: g = (i,f,g,o) preactivations, updates c, returns h
static __device__ __forceinline__ float lstm_cell(const f32x4 g, float& c) {
    float iv = sigmoid_f(g[0]);
    float fv = sigmoid_f(g[1]);
    float gg = tanh_f(g[2]);
    float ov = sigmoid_f(g[3]);
    c = fmaf(fv, c, iv * gg);
    return ov * tanh_f(c);
}

// ---------------------------------------------------------------------------
// Split-bf16 GEMM (structure validated R2-R7): xp(t,b,n') permuted output.
// R8: staging conversion via v_cvt_pk_bf16_f32 (2 ops/4 vals vs ~12 software).
// ---------------------------------------------------------------------------
#define PK 40   // LDS row stride in halves (80 B)

__global__ __launch_bounds__(256) void gemm_split_bf16(
    const float* __restrict__ A, const float* __restrict__ Bw,
    const float* __restrict__ b1, const float* __restrict__ b2,
    float* __restrict__ C, int M, int N, int K)
{
    __shared__ unsigned short Ah[128 * PK], Al[128 * PK];
    __shared__ unsigned short Bh[128 * PK], Bl[128 * PK];

    const int tid = threadIdx.x;
    const int l = tid & 63;
    const int w = tid >> 6;
    const int wr = w >> 1, wc = w & 1;
    const int bm = blockIdx.y, bn = blockIdx.x;

    f32x4 acc[4][4];
#pragma unroll
    for (int m = 0; m < 4; ++m)
#pragma unroll
        for (int n = 0; n < 4; ++n) acc[m][n] = f32x4{0.f, 0.f, 0.f, 0.f};

    const float* Ab = A + (size_t)(bm * 128) * K;

    for (int k0 = 0; k0 < K; k0 += 32) {
        __syncthreads();
#pragma unroll
        for (int q = 0; q < 4; ++q) {
            int fid = tid + 256 * q;
            int r = fid >> 3;
            int kk = (fid & 7) << 2;
            int n = bn * 128 + r;
            int orign = ((n & 3) << 7) | (n >> 2);
            float4 av = *(const float4*)(Ab + (size_t)r * K + k0 + kk);
            float4 bv = *(const float4*)(Bw + (size_t)orign * K + k0 + kk);
            int off = r * PK + kk;
            // A tile: hi/lo split via HW packed cvt
            unsigned h01 = cvt_pk_bf16(av.x, av.y), h23 = cvt_pk_bf16(av.z, av.w);
            float l0 = av.x - __uint_as_float(h01 << 16);
            float l1 = av.y - __uint_as_float(h01 & 0xffff0000u);
            float l2 = av.z - __uint_as_float(h23 << 16);
            float l3 = av.w - __uint_as_float(h23 & 0xffff0000u);
            unsigned lo01 = cvt_pk_bf16(l0, l1), lo23 = cvt_pk_bf16(l2, l3);
            *(uint2*)&Ah[off] = uint2{h01, h23};
            *(uint2*)&Al[off] = uint2{lo01, lo23};
            // B tile
            h01 = cvt_pk_bf16(bv.x, bv.y); h23 = cvt_pk_bf16(bv.z, bv.w);
            l0 = bv.x - __uint_as_float(h01 << 16);
            l1 = bv.y - __uint_as_float(h01 & 0xffff0000u);
            l2 = bv.z - __uint_as_float(h23 << 16);
            l3 = bv.w - __uint_as_float(h23 & 0xffff0000u);
            lo01 = cvt_pk_bf16(l0, l1); lo23 = cvt_pk_bf16(l2, l3);
            *(uint2*)&Bh[off] = uint2{h01, h23};
            *(uint2*)&Bl[off] = uint2{lo01, lo23};
        }
        __syncthreads();

        bf16x8 aH[4], aL[4], bH[4], bL[4];
#pragma unroll
        for (int m = 0; m < 4; ++m) {
            int row = wr * 64 + m * 16 + (l & 15);
            int off = row * PK + 8 * (l >> 4);
            aH[m] = *(const bf16x8*)&Ah[off];
            aL[m] = *(const bf16x8*)&Al[off];
        }
#pragma unroll
        for (int n = 0; n < 4; ++n) {
            int row = wc * 64 + n * 16 + (l & 15);
            int off = row * PK + 8 * (l >> 4);
            bH[n] = *(const bf16x8*)&Bh[off];
            bL[n] = *(const bf16x8*)&Bl[off];
        }
#pragma unroll
        for (int m = 0; m < 4; ++m)
#pragma unroll
            for (int n = 0; n < 4; ++n) {
                acc[m][n] = __builtin_amdgcn_mfma_f32_16x16x32_bf16(aH[m], bH[n], acc[m][n], 0, 0, 0);
                acc[m][n] = __builtin_amdgcn_mfma_f32_16x16x32_bf16(aH[m], bL[n], acc[m][n], 0, 0, 0);
                acc[m][n] = __builtin_amdgcn_mfma_f32_16x16x32_bf16(aL[m], bH[n], acc[m][n], 0, 0, 0);
            }
    }

#pragma unroll
    for (int n = 0; n < 4; ++n) {
        int cg = bn * 128 + wc * 64 + n * 16 + (l & 15);
        int orig = ((cg & 3) << 7) | (cg >> 2);
        float bias = b1[orig] + b2[orig];
        size_t cbase = (size_t)(cg >> 6) * 1024 + ((cg >> 4) & 3) * 256 + (cg & 15);
#pragma unroll
        for (int m = 0; m < 4; ++m) {
            int r0 = bm * 128 + wr * 64 + m * 16 + ((l >> 4) << 2);
            f32x4 v = acc[m][n];
#pragma unroll
            for (int i = 0; i < 4; ++i) {
                int r = r0 + i;
                int t = r & 255, b = r >> 8;
                C[(size_t)t * 32768 + (size_t)(b >> 4) * 8192 + cbase + (b & 15) * 16] = v[i] + bias;
            }
        }
    }
}

// ---------------------------------------------------------------------------
// bias1p[n'] = bih1[orig]+bhh1[orig], permuted to gate-interleaved order.
// ---------------------------------------------------------------------------
__global__ void prep_bias1(const float* __restrict__ bih1,
                           const float* __restrict__ bhh1,
                           float* __restrict__ bias1p)
{
    int n = threadIdx.x;                 // 512
    int orig = ((n & 3) << 7) | (n >> 2);
    bias1p[n] = bih1[orig] + bhh1[orig];
}

// ---------------------------------------------------------------------------
// FUSED two-layer LSTM, 16-wave version (R8).
// 4 blocks x 16 batches, 1024 threads = 16 waves, 4 waves/SIMD (2x the
// latency hiding of the 8-wave R6/R7 versions). Wave w owns gate rows
// 32w..32w+31 (2 m-tiles) of BOTH layers; layer 1 is one K=256 matvec
// [Wih1|Whh1] @ [h0_p; h1_{p-1}].
// Register budget (hard 128-VGPR cap at 16 waves/CU): Whh0+Wih1 frags in
// VGPRs (64), Whh1 frags SELF-SPILLED TO LDS at startup (128 KB) and
// streamed back per phase as stride-1 conflict-free ds_read_b128.
// One barrier per phase; h double-buffered fp16 in LDS.
// ---------------------------------------------------------------------------
__global__ __launch_bounds__(1024) void lstm_fused16(
    const float* __restrict__ xp,      // permuted xp0 layout (see top)
    const float* __restrict__ Whh0,    // [512,128] original layout
    const float* __restrict__ Wih1,    // [512,128]
    const float* __restrict__ Whh1,    // [512,128]
    const float* __restrict__ bias1p,  // [512] permuted (prep_bias1)
    const float* __restrict__ Wfc,     // [128]
    const float* __restrict__ bfc,     // [1]
    float* __restrict__ out)           // [64]
{
    const int tid = threadIdx.x;
    const int l  = tid & 63;
    const int w  = tid >> 6;     // wave 0..15
    const int lb = l & 15;       // batch lane / MFMA col
    const int lg = l >> 4;       // 0..3
    const int blk = blockIdx.x;

    __shared__ ushort h0b[2][GB][HPAD];
    __shared__ ushort h1b[2][GB][HPAD];
    __shared__ float red[16][GB];
    __shared__ _Float16 W1[32 * 4 * 64 * 8];   // Whh1 frags: [(mt*4+kt)*64+l]*8, 128 KB

    for (int i = tid; i < 2 * GB * HPAD; i += 1024) {
        ((ushort*)h0b)[i] = 0;
        ((ushort*)h1b)[i] = 0;
    }

    // ---- weight fragments: rows rp=(2w+i)*16+lb, orig=g*128+u -------------
    f16x8 wf0[2][4], wi1[2][4];              // 32 + 32 VGPR
#pragma unroll
    for (int i = 0; i < 2; ++i) {
        int mt = 2 * w + i;
        int rp = mt * 16 + lb;
        int orig = ((rp & 3) << 7) | (rp >> 2);
        const float* p0 = Whh0 + (size_t)orig * HH;
        const float* p1 = Wih1 + (size_t)orig * HH;
        const float* p2 = Whh1 + (size_t)orig * HH;
#pragma unroll
        for (int kt = 0; kt < 4; ++kt) {
            float4 x0, x1;
            f16x8 f;
            x0 = *(const float4*)(p0 + kt * 32 + lg * 8);
            x1 = *(const float4*)(p0 + kt * 32 + lg * 8 + 4);
            f[0]=(_Float16)x0.x; f[1]=(_Float16)x0.y; f[2]=(_Float16)x0.z; f[3]=(_Float16)x0.w;
            f[4]=(_Float16)x1.x; f[5]=(_Float16)x1.y; f[6]=(_Float16)x1.z; f[7]=(_Float16)x1.w;
            wf0[i][kt] = f;
            x0 = *(const float4*)(p1 + kt * 32 + lg * 8);
            x1 = *(const float4*)(p1 + kt * 32 + lg * 8 + 4);
            f[0]=(_Float16)x0.x; f[1]=(_Float16)x0.y; f[2]=(_Float16)x0.z; f[3]=(_Float16)x0.w;
            f[4]=(_Float16)x1.x; f[5]=(_Float16)x1.y; f[6]=(_Float16)x1.z; f[7]=(_Float16)x1.w;
            wi1[i][kt] = f;
            x0 = *(const float4*)(p2 + kt * 32 + lg * 8);
            x1 = *(const float4*)(p2 + kt * 32 + lg * 8 + 4);
            f[0]=(_Float16)x0.x; f[1]=(_Float16)x0.y; f[2]=(_Float16)x0.z; f[3]=(_Float16)x0.w;
            f[4]=(_Float16)x1.x; f[5]=(_Float16)x1.y; f[6]=(_Float16)x1.z; f[7]=(_Float16)x1.w;
            *(f16x8*)&W1[((size_t)(mt * 4 + kt) * 64 + l) * 8] = f;   // self-spill
        }
    }

    // xp fragment address for (t, m-tile index i)
    const float* xb = xp + (size_t)blk * 8192 + lb * 16 + lg * 4;
    auto xaddr = [&](int t, int i) {
        int mt = 2 * w + i;
        return xb + (size_t)t * 32768 + (mt >> 2) * 1024 + (mt & 3) * 256;
    };

    f32x4 Xa = *(const f32x4*)xaddr(0, 0);
    f32x4 Xb = *(const f32x4*)xaddr(0, 1);

    float c0[2] = {0.f, 0.f}, c1[2] = {0.f, 0.f}, hv[2];
    __syncthreads();   // LDS zeroing + W1 staging complete

    // ---- prologue: h0_0 = act(xp0[0]), c_{-1}=0 ---------------------------
    {
        float h;
        h = lstm_cell(Xa, c0[0]);  h0b[0][lb][8 * w + lg]     = hbits(h);
        h = lstm_cell(Xb, c0[1]);  h0b[0][lb][8 * w + 4 + lg] = hbits(h);
    }
    Xa = *(const f32x4*)xaddr(1, 0);
    Xb = *(const f32x4*)xaddr(1, 1);
    __syncthreads();   // h0_0 visible

    // ---- main loop: 256 phases --------------------------------------------
    for (int p = 0; p < TT; ++p) {
        const int rb = p & 1, wb = rb ^ 1;

        f32x4 A00 = Xa, A01 = Xb;                       // gates0 = xp0[p+1] + ...
        {   // prefetch next xp (in-flight across the phase)
            int tn = (p + 2 < TT) ? p + 2 : TT - 1;
            Xa = *(const f32x4*)xaddr(tn, 0);
            Xb = *(const f32x4*)xaddr(tn, 1);
        }
        f32x4 A10 = *(const f32x4*)(bias1p + (2 * w) * 16 + lg * 4);       // gates1 init
        f32x4 A11 = *(const f32x4*)(bias1p + (2 * w + 1) * 16 + lg * 4);

        // shared h0_p fragments feed Whh0 (L0) and Wih1 (L1a)
#pragma unroll
        for (int kt = 0; kt < 4; ++kt) {
            union { uint4 u; f16x8 h; } cvt;
            cvt.u = *(const uint4*)&h0b[rb][lb][kt * 32 + lg * 8];
            f16x8 bh = cvt.h;
            A00 = __builtin_amdgcn_mfma_f32_16x16x32_f16(wf0[0][kt], bh, A00, 0, 0, 0);
            A01 = __builtin_amdgcn_mfma_f32_16x16x32_f16(wf0[1][kt], bh, A01, 0, 0, 0);
            A10 = __builtin_amdgcn_mfma_f32_16x16x32_f16(wi1[0][kt], bh, A10, 0, 0, 0);
            A11 = __builtin_amdgcn_mfma_f32_16x16x32_f16(wi1[1][kt], bh, A11, 0, 0, 0);
        }
        // L0 activations retire A00/A01 early (caps live VGPRs)
        {
            float h;
            h = lstm_cell(A00, c0[0]);  h0b[wb][lb][8 * w + lg]     = hbits(h);
            h = lstm_cell(A01, c0[1]);  h0b[wb][lb][8 * w + 4 + lg] = hbits(h);
        }
        // L1b: Whh1 (frags streamed from LDS) @ h1_{p-1}
#pragma unroll
        for (int kt = 0; kt < 4; ++kt) {
            union { uint4 u; f16x8 h; } cvt;
            cvt.u = *(const uint4*)&h1b[rb][lb][kt * 32 + lg * 8];
            f16x8 bh = cvt.h;
            f16x8 w0 = *(const f16x8*)&W1[((size_t)((2 * w) * 4 + kt) * 64 + l) * 8];
            f16x8 w1 = *(const f16x8*)&W1[((size_t)((2 * w + 1) * 4 + kt) * 64 + l) * 8];
            A10 = __builtin_amdgcn_mfma_f32_16x16x32_f16(w0, bh, A10, 0, 0, 0);
            A11 = __builtin_amdgcn_mfma_f32_16x16x32_f16(w1, bh, A11, 0, 0, 0);
        }
        {
            float h;
            h = lstm_cell(A10, c1[0]);  hv[0] = h;  h1b[wb][lb][8 * w + lg]     = hbits(h);
            h = lstm_cell(A11, c1[1]);  hv[1] = h;  h1b[wb][lb][8 * w + 4 + lg] = hbits(h);
        }
        __syncthreads();
    }

    // ---- fused FC head: out[b] = sum_u h1_255[u]*Wfc[u] + bfc -------------
    float pr = fmaf(hv[0], Wfc[8 * w + lg], hv[1] * Wfc[8 * w + 4 + lg]);
    pr += __shfl_xor(pr, 16, 64);
    pr += __shfl_xor(pr, 32, 64);
    if (l < GB) red[w][l] = pr;
    __syncthreads();
    if (tid < GB) {
        float s = bfc[0];
#pragma unroll
        for (int q = 0; q < 16; ++q) s += red[q][tid];
        out[blk * GB + tid] = s;
    }
}

// ---------------------------------------------------------------------------
extern "C" void kernel_launch(void* const* d_in, const int* in_sizes, int n_in,
                              void* d_out, int out_size, void* d_ws, size_t ws_size,
                              hipStream_t stream)
{
    const float* x    = (const float*)d_in[0];
    const float* Wih0 = (const float*)d_in[1];
    const float* Whh0 = (const float*)d_in[2];
    const float* bih0 = (const float*)d_in[3];
    const float* bhh0 = (const float*)d_in[4];
    const float* Wih1 = (const float*)d_in[5];
    const float* Whh1 = (const float*)d_in[6];
    const float* bih1 = (const float*)d_in[7];
    const float* bhh1 = (const float*)d_in[8];
    const float* Wfc  = (const float*)d_in[9];
    const float* bfc  = (const float*)d_in[10];
    float* out = (float*)d_out;

    const int M = BATCH * TT;                    // 16384
    float* xp      = (float*)d_ws;               // [16384,512] permuted
    float* bias1p  = xp + (size_t)M * G4;        // [512]

    // 1) xp0 = x @ Wih0_perm^T + bih0 + bhh0 -> permuted layout (34.4 GFLOP)
    gemm_split_bf16<<<dim3(G4 / 128, M / 128), 256, 0, stream>>>(
        x, Wih0, bih0, bhh0, xp, M, G4, DD);

    // 2) permuted layer-1 bias
    prep_bias1<<<1, G4, 0, stream>>>(bih1, bhh1, bias1p);

    // 3) fused 2-layer recurrence + FC head (16 waves, 4 blocks)
    lstm_fused16<<<BATCH / GB, 1024, 0, stream>>>(
        xp, Whh0, Wih1, Whh1, bias1p, Wfc, bfc, out);
}